// Round 8
// baseline (171.871 us; speedup 1.0000x reference)
//
#include <hip/hip_runtime.h>
#include <hip/hip_bf16.h>

#define HEADS 4
#define DH    128
#define CIN   256
#define NPIX  16384
#define NB    4
#define HID   512

typedef __attribute__((ext_vector_type(8))) short bf16x8;
typedef __attribute__((ext_vector_type(4))) float f32x4;

__device__ __forceinline__ unsigned short f2bfu(float f) {
    union { __hip_bfloat16 h; unsigned short u; } cv;
    cv.h = __float2bfloat16(f);
    return cv.u;
}

// ---- async global->LDS, 16B per lane --------------------------------------
typedef const __attribute__((address_space(1))) unsigned char* gas_t;
typedef __attribute__((address_space(3))) unsigned char* las_t;
__device__ __forceinline__ void glds16(const void* g, void* s) {
    __builtin_amdgcn_global_load_lds((gas_t)g, (las_t)s, 16, 0, 0);
}

// Fragment-tile: 16(row) x 32(k) bf16 = 512 ushorts, lane-major:
// element (row r, k) at us = (r + 16*(k>>3))*8 + (k&7); lane l owns us l*8..l*8+7.

// ---------------------------------------------------------------------------
// K0a: x[b][c][n] fp32 -> xt2 (frag tiles rows=n,k=c), xbf2 (frag tiles rows=c,k=n)
// grid (256, 4, 4), block 256
// ---------------------------------------------------------------------------
__global__ __launch_bounds__(256) void xt_convert2(const float* __restrict__ x,
                                                   unsigned short* __restrict__ xt2,
                                                   unsigned short* __restrict__ xbf2)
{
    __shared__ float tile[64][66];
    const int b = blockIdx.z, c0 = blockIdx.y * 64, n0 = blockIdx.x * 64;
    const int t = threadIdx.x, lane = t & 63, wid = t >> 6;
    const float* xb = x + ((size_t)b * CIN + c0) * NPIX + n0;
#pragma unroll
    for (int p = 0; p < 4; ++p) {
        const int c = p * 16 + (t >> 4);
        const int n = (t & 15) * 4;
        float4 v = *reinterpret_cast<const float4*>(xb + (size_t)c * NPIX + n);
        tile[c][n + 0] = v.x; tile[c][n + 1] = v.y;
        tile[c][n + 2] = v.z; tile[c][n + 3] = v.w;
    }
    __syncthreads();
    // xt2: tiles (n16, c32): idx = ((b*1024 + n/16)*8 + c/32)
#pragma unroll
    for (int rr = 0; rr < 2; ++rr) {
        const int tid  = wid * 2 + rr;
        const int n16l = tid >> 1, c32l = tid & 1;
        const int nl   = n16l * 16 + (lane & 15);
        const int cb   = c32l * 32 + (lane >> 4) * 8;
        unsigned short u8[8];
#pragma unroll
        for (int j = 0; j < 8; ++j) u8[j] = f2bfu(tile[cb + j][nl]);
        *reinterpret_cast<uint4*>(
            xt2 + (((size_t)b * 1024 + (n0 >> 4) + n16l) * 8 + (c0 >> 5) + c32l) * 512 + lane * 8)
            = *reinterpret_cast<const uint4*>(u8);
    }
    // xbf2: tiles (c16, n32): idx = ((b*16 + c/16)*512 + n/32)
#pragma unroll
    for (int rr = 0; rr < 2; ++rr) {
        const int tid  = wid * 2 + rr;
        const int c16l = tid >> 1, n32l = tid & 1;
        const int cr   = c16l * 16 + (lane & 15);
        const int nb   = n32l * 32 + (lane >> 4) * 8;
        unsigned short u8[8];
#pragma unroll
        for (int j = 0; j < 8; ++j) u8[j] = f2bfu(tile[cr][nb + j]);
        *reinterpret_cast<uint4*>(
            xbf2 + (((size_t)b * 16 + (c0 >> 4) + c16l) * 512 + (n0 >> 5) + n32l) * 512 + lane * 8)
            = *reinterpret_cast<const uint4*>(u8);
    }
}

// ---------------------------------------------------------------------------
// K0b: all weight frag tiles (unchanged from R7).
// ---------------------------------------------------------------------------
__global__ __launch_bounds__(256) void wconv3(const float* __restrict__ w_qkv,
                                              const float* __restrict__ w_out,
                                              unsigned short* __restrict__ WkF,
                                              unsigned short* __restrict__ WvF,
                                              unsigned short* __restrict__ WqTF,
                                              unsigned short* __restrict__ WoF)
{
    const int t = threadIdx.x, lane = t & 63, wid = t >> 6;
    const int tile = blockIdx.x * 4 + wid;
    unsigned short u8[8];
    unsigned short* dst;
    if (tile < 256) {                       // WkF [h][d16 8][c32 8]
        const int h = tile >> 6, d16 = (tile >> 3) & 7, c32 = tile & 7;
        const float* src = w_qkv + (size_t)(512 + h * 128 + d16 * 16 + (lane & 15)) * CIN
                         + c32 * 32 + (lane >> 4) * 8;
#pragma unroll
        for (int j = 0; j < 8; ++j) u8[j] = f2bfu(src[j]);
        dst = WkF + (size_t)tile * 512 + lane * 8;
    } else if (tile < 512) {                // WvF [h][e16 8][c32 8]
        const int t2 = tile - 256;
        const int h = t2 >> 6, e16 = (t2 >> 3) & 7, c32 = t2 & 7;
        const float* src = w_qkv + (size_t)(1024 + h * 128 + e16 * 16 + (lane & 15)) * CIN
                         + c32 * 32 + (lane >> 4) * 8;
#pragma unroll
        for (int j = 0; j < 8; ++j) u8[j] = f2bfu(src[j]);
        dst = WvF + (size_t)t2 * 512 + lane * 8;
    } else if (tile < 768) {                // WqTF [h][c16 16][d32 4]
        const int t2 = tile - 512;
        const int h = t2 >> 6, c16 = (t2 >> 2) & 15, d32 = t2 & 3;
#pragma unroll
        for (int j = 0; j < 8; ++j)
            u8[j] = f2bfu(w_qkv[(size_t)(h * 128 + d32 * 32 + (lane >> 4) * 8 + j) * CIN
                                + c16 * 16 + (lane & 15)]);
        dst = WqTF + (size_t)t2 * 512 + lane * 8;
    } else {                                // WoF [o16 16][m32 16]
        const int t2 = tile - 768;
        const int o16 = t2 >> 4, m32 = t2 & 15;
        const float* src = w_out + (size_t)(o16 * 16 + (lane & 15)) * HID
                         + m32 * 32 + (lane >> 4) * 8;
#pragma unroll
        for (int j = 0; j < 8; ++j) u8[j] = f2bfu(src[j]);
        dst = WoF + (size_t)t2 * 512 + lane * 8;
    }
    *reinterpret_cast<uint4*>(dst) = *reinterpret_cast<const uint4*>(u8);
}

// ---------------------------------------------------------------------------
// K1: fused kg, wave-local P, ONE barrier per nt.
// Block = (ns 32, h 4, b 4) -> 512 blocks = 2/CU.  512 threads = 8 waves.
// Wave w owns d16 slice w (16 d rows) end-to-end:
//   GEMM1 (swapped): P[32n x 16d] = mfma(xt_frag, Wk_frag)   16 MFMA
//   exp -> pack u32 -> private sP tile (A-frag layout)        wave-local
//   GEMM2: G[16d x 256c] += mfma(P_frag, xbf_frag)            16 MFMA
// LDS 72 KB, aW persistent 32 VGPR, accG 64 VGPR.
// ---------------------------------------------------------------------------
__global__ __launch_bounds__(512, 4) void kg_fused5(const unsigned short* __restrict__ xt2,
                                                    const unsigned short* __restrict__ xbf2,
                                                    const unsigned short* __restrict__ WkF,
                                                    float* __restrict__ G,
                                                    float* __restrict__ S)
{
    __shared__ unsigned short sXT[2][16 * 512];   // 2 x 16 KB (2 n16 x 8 c32)
    __shared__ unsigned short sXB[2][16 * 512];   // 2 x 16 KB (16 c16 x 1 n32)
    __shared__ unsigned short sP[8 * 512];        // 8 KB: one private tile per wave

    const int t = threadIdx.x, lane = t & 63, wid = t >> 6;
    const int ns = blockIdx.x, h = blockIdx.y, b = blockIdx.z;
    const int bh = b * 4 + h;
    const int q = lane >> 4, cl = lane & 15;

    // persistent Wk fragments for this wave's d16 slice: 32 VGPR
    bf16x8 aW[8];
#pragma unroll
    for (int ks = 0; ks < 8; ++ks)
        aW[ks] = *reinterpret_cast<const bf16x8*>(
            WkF + ((size_t)((h * 8 + wid) * 8 + ks)) * 512 + lane * 8);

    f32x4 accG[16] = {};
    float Sacc = 0.f;

#define STAGE(nt_, buf_)                                                          \
    {                                                                             \
        _Pragma("unroll")                                                         \
        for (int q2 = 0; q2 < 2; ++q2) {                                          \
            const int tl = wid * 2 + q2;            /* n16 = tl>>3, c32 = tl&7 */ \
            glds16(xt2 + (((size_t)(b * 1024 + ns * 32 + (nt_) * 2 + (tl >> 3))) * 8 \
                          + (tl & 7)) * 512 + lane * 8,                           \
                   sXT[buf_] + (size_t)tl * 512);                                 \
        }                                                                         \
        _Pragma("unroll")                                                         \
        for (int q2 = 0; q2 < 2; ++q2) {                                          \
            const int tl = wid * 2 + q2;            /* c16 = tl */                \
            glds16(xbf2 + (((size_t)(b * 16 + tl)) * 512 + ns * 16 + (nt_)) * 512 \
                          + lane * 8,                                             \
                   sXB[buf_] + (size_t)tl * 512);                                 \
        }                                                                         \
    }

    STAGE(0, 0);
    __syncthreads();

    int cur = 0;
    for (int nt = 0; nt < 16; ++nt) {
        if (nt < 15) STAGE(nt + 1, cur ^ 1);

        // ---- GEMM1 (swapped): acc1[s][r] = P[n = s*16 + q*4 + r][d = cl] ----
        f32x4 acc1[2] = {};
#pragma unroll
        for (int ks = 0; ks < 8; ++ks) {
            const bf16x8 a0 = *reinterpret_cast<const bf16x8*>(
                &sXT[cur][(0 * 8 + ks) * 512 + lane * 8]);
            const bf16x8 a1 = *reinterpret_cast<const bf16x8*>(
                &sXT[cur][(1 * 8 + ks) * 512 + lane * 8]);
            acc1[0] = __builtin_amdgcn_mfma_f32_16x16x32_bf16(a0, aW[ks], acc1[0], 0, 0, 0);
            acc1[1] = __builtin_amdgcn_mfma_f32_16x16x32_bf16(a1, aW[ks], acc1[1], 0, 0, 0);
        }

        // ---- exp, pack pairs to u32, write into private A-frag tile ----
        // value (d=cl, n=s*16+q*4+2p+{0,1}) -> us=(cl+16*(2s+(q>>1)))*8+(q&1)*4+2p
        unsigned* sPw = reinterpret_cast<unsigned*>(&sP[wid * 512]);
#pragma unroll
        for (int s = 0; s < 2; ++s)
#pragma unroll
            for (int p = 0; p < 2; ++p) {
                const float e0 = __expf(acc1[s][2 * p]);
                const float e1 = __expf(acc1[s][2 * p + 1]);
                Sacc += e0 + e1;
                const unsigned pk = (unsigned)f2bfu(e0) | ((unsigned)f2bfu(e1) << 16);
                const int us = (cl + 16 * (2 * s + (q >> 1))) * 8 + (q & 1) * 4 + 2 * p;
                sPw[us >> 1] = pk;
            }
        // wave-local RAW: compiler inserts lgkmcnt wait; no barrier needed
        const bf16x8 pa = *reinterpret_cast<const bf16x8*>(&sP[wid * 512 + lane * 8]);

        // ---- GEMM2: accG[fj] = G[16d x 16c] fj-th c-frag, K = 32 n ----
#pragma unroll
        for (int fj = 0; fj < 16; ++fj) {
            const bf16x8 bb = *reinterpret_cast<const bf16x8*>(
                &sXB[cur][fj * 512 + lane * 8]);
            accG[fj] = __builtin_amdgcn_mfma_f32_16x16x32_bf16(pa, bb, accG[fj], 0, 0, 0);
        }

        __syncthreads();   // drains next-tile glds (issued a full phase ago) + WAR on bufs
        cur ^= 1;
    }
#undef STAGE

    // ---- S rowsums: lane holds partial for d = wid*16 + cl; reduce q-groups ----
    {
        float v = Sacc;
        v += __shfl_xor(v, 16);
        v += __shfl_xor(v, 32);
        if (lane < 16)
            atomicAdd(&S[bh * 128 + wid * 16 + lane], v);
    }

    // ---- G accumulate: D row = (lane>>4)*4+r -> d, col = cl -> c ----
#pragma unroll
    for (int fj = 0; fj < 16; ++fj)
#pragma unroll
        for (int r = 0; r < 4; ++r) {
            const int d = wid * 16 + q * 4 + r;
            const int c = fj * 16 + cl;
            atomicAdd(&G[(size_t)bh * 32768 + d * 256 + c], accG[fj][r]);
        }
}

// ---------------------------------------------------------------------------
// C1: per bh: ctx = (G/S) x Wv^T, then Abar = ctx^T x Wq -> AbarF frag tiles.
// grid 16, block 256 (unchanged from R7)
// ---------------------------------------------------------------------------
__global__ __launch_bounds__(256) void c1_kernel(const float* __restrict__ G,
                                                 const float* __restrict__ S,
                                                 const unsigned short* __restrict__ WvF,
                                                 const unsigned short* __restrict__ WqTF,
                                                 unsigned short* __restrict__ AbarF)
{
    __shared__ unsigned short sCtx[32 * 512];
    const int t = threadIdx.x, lane = t & 63, wid = t >> 6;
    const int bh = blockIdx.x, b = bh >> 2, h = bh & 3;
    const int cl = lane & 15, r0q = (lane >> 4) * 4;
    const int wr = wid >> 1, wc = wid & 1;
    const float* Gb = G + (size_t)bh * 32768;

    float invs[4];
#pragma unroll
    for (int fi = 0; fi < 4; ++fi)
        invs[fi] = 1.0f / S[bh * 128 + wr * 64 + fi * 16 + cl];

    f32x4 acc[4][4] = {};
#pragma unroll
    for (int ks = 0; ks < 8; ++ks) {
        bf16x8 a[4], bb[4];
#pragma unroll
        for (int fi = 0; fi < 4; ++fi) {
            const float* gp = Gb + (size_t)(wr * 64 + fi * 16 + cl) * 256
                            + ks * 32 + (lane >> 4) * 8;
            const float4 v0 = *reinterpret_cast<const float4*>(gp);
            const float4 v1 = *reinterpret_cast<const float4*>(gp + 4);
            unsigned short u8[8] = {
                f2bfu(v0.x * invs[fi]), f2bfu(v0.y * invs[fi]),
                f2bfu(v0.z * invs[fi]), f2bfu(v0.w * invs[fi]),
                f2bfu(v1.x * invs[fi]), f2bfu(v1.y * invs[fi]),
                f2bfu(v1.z * invs[fi]), f2bfu(v1.w * invs[fi]) };
            a[fi] = *reinterpret_cast<const bf16x8*>(u8);
        }
#pragma unroll
        for (int fj = 0; fj < 4; ++fj)
            bb[fj] = *reinterpret_cast<const bf16x8*>(
                WvF + ((size_t)(h * 8 + wc * 4 + fj) * 8 + ks) * 512 + lane * 8);
#pragma unroll
        for (int fi = 0; fi < 4; ++fi)
#pragma unroll
            for (int fj = 0; fj < 4; ++fj)
                acc[fi][fj] = __builtin_amdgcn_mfma_f32_16x16x32_bf16(
                    a[fi], bb[fj], acc[fi][fj], 0, 0, 0);
    }

#pragma unroll
    for (int fi = 0; fi < 4; ++fi)
#pragma unroll
        for (int fj = 0; fj < 4; ++fj)
#pragma unroll
            for (int r = 0; r < 4; ++r) {
                const int us = (cl + 16 * ((fi & 1) * 2 + ((r0q + r) >> 3))) * 8 + ((r0q + r) & 7);
                sCtx[((wc * 4 + fj) * 4 + wr * 2 + (fi >> 1)) * 512 + us] = f2bfu(acc[fi][fj][r]);
            }
    __syncthreads();

    const int we = wid >> 1, wcq = wid & 1;
    f32x4 acc2[4][8] = {};
#pragma unroll
    for (int ks = 0; ks < 4; ++ks) {
        bf16x8 a2[4], b2[8];
#pragma unroll
        for (int fi = 0; fi < 4; ++fi)
            a2[fi] = *reinterpret_cast<const bf16x8*>(
                &sCtx[((we * 4 + fi) * 4 + ks) * 512 + lane * 8]);
#pragma unroll
        for (int fj = 0; fj < 8; ++fj)
            b2[fj] = *reinterpret_cast<const bf16x8*>(
                WqTF + ((size_t)(h * 16 + wcq * 8 + fj) * 4 + ks) * 512 + lane * 8);
#pragma unroll
        for (int fi = 0; fi < 4; ++fi)
#pragma unroll
            for (int fj = 0; fj < 8; ++fj)
                acc2[fi][fj] = __builtin_amdgcn_mfma_f32_16x16x32_bf16(
                    a2[fi], b2[fj], acc2[fi][fj], 0, 0, 0);
    }

#pragma unroll
    for (int fi = 0; fi < 4; ++fi)
#pragma unroll
        for (int fj = 0; fj < 8; ++fj)
#pragma unroll
            for (int r = 0; r < 4; ++r) {
                const int c16 = wcq * 8 + fj;
                const int m32 = h * 4 + we * 2 + (fi >> 1);
                const int us  = (cl + 16 * ((fi & 1) * 2 + ((r0q + r) >> 3))) * 8 + ((r0q + r) & 7);
                AbarF[((size_t)(b * 16 + c16) * 16 + m32) * 512 + us] = f2bfu(acc2[fi][fj][r]);
            }
}

// ---------------------------------------------------------------------------
// C2: F[b][256o x 64c] = Wo x Abar (K=512), no LDS. (unchanged from R7)
// ---------------------------------------------------------------------------
__global__ __launch_bounds__(256) void c2_kernel(const unsigned short* __restrict__ WoF,
                                                 const unsigned short* __restrict__ AbarF,
                                                 unsigned short* __restrict__ F2)
{
    const int t = threadIdx.x, lane = t & 63, wid = t >> 6;
    const int csp = blockIdx.x, b = blockIdx.y;
    const int cl = lane & 15, r0q = (lane >> 4) * 4;

    f32x4 acc[4][4] = {};
#pragma unroll
    for (int ks = 0; ks < 16; ++ks) {
        bf16x8 a[4], bb[4];
#pragma unroll
        for (int fi = 0; fi < 4; ++fi)
            a[fi] = *reinterpret_cast<const bf16x8*>(
                WoF + ((size_t)(wid * 4 + fi) * 16 + ks) * 512 + lane * 8);
#pragma unroll
        for (int fj = 0; fj < 4; ++fj)
            bb[fj] = *reinterpret_cast<const bf16x8*>(
                AbarF + ((size_t)(b * 16 + csp * 4 + fj) * 16 + ks) * 512 + lane * 8);
#pragma unroll
        for (int fi = 0; fi < 4; ++fi)
#pragma unroll
            for (int fj = 0; fj < 4; ++fj)
                acc[fi][fj] = __builtin_amdgcn_mfma_f32_16x16x32_bf16(
                    a[fi], bb[fj], acc[fi][fj], 0, 0, 0);
    }

#pragma unroll
    for (int fi = 0; fi < 4; ++fi)
#pragma unroll
        for (int fj = 0; fj < 4; ++fj)
#pragma unroll
            for (int r = 0; r < 4; ++r) {
                const int o16 = wid * 4 + fi;
                const int c32 = csp * 2 + (fj >> 1);
                const int us  = ((r0q + r) + 16 * ((fj & 1) * 2 + (cl >> 3))) * 8 + (cl & 7);
                F2[((size_t)(b * 16 + o16) * 8 + c32) * 512 + us] = f2bfu(acc[fi][fj][r]);
            }
}

// ---------------------------------------------------------------------------
// K6: out GEMM (unchanged from R7).
// ---------------------------------------------------------------------------
__global__ __launch_bounds__(256, 2) void out_gemm3(const unsigned short* __restrict__ xt2,
                                                    const unsigned short* __restrict__ F2,
                                                    const float* __restrict__ b_out,
                                                    float* __restrict__ out)
{
    __shared__ unsigned short sXT[64 * 512];
    const int t = threadIdx.x, lane = t & 63, wid = t >> 6;
    const int n0 = blockIdx.x * 128, m0 = blockIdx.y * 128, b = blockIdx.z;
    const int wr = wid >> 1, wc = wid & 1;

    const unsigned short* src = xt2 + ((size_t)(b * 1024 + (n0 >> 4)) * 8) * 512;
#pragma unroll
    for (int p = 0; p < 16; ++p) {
        const int tl = p * 4 + wid;
        glds16(src + (size_t)tl * 512 + lane * 8, sXT + (size_t)tl * 512);
    }
    __syncthreads();

    f32x4 acc[4][4] = {};
#pragma unroll
    for (int ks = 0; ks < 8; ++ks) {
        bf16x8 a[4], bb[4];
#pragma unroll
        for (int fi = 0; fi < 4; ++fi)
            a[fi] = *reinterpret_cast<const bf16x8*>(
                F2 + (((size_t)b * 16 + (m0 >> 4) + wr * 4 + fi) * 8 + ks) * 512 + lane * 8);
#pragma unroll
        for (int fj = 0; fj < 4; ++fj)
            bb[fj] = *reinterpret_cast<const bf16x8*>(
                &sXT[((wc * 4 + fj) * 8 + ks) * 512 + lane * 8]);
#pragma unroll
        for (int fi = 0; fi < 4; ++fi)
#pragma unroll
            for (int fj = 0; fj < 4; ++fj)
                acc[fi][fj] = __builtin_amdgcn_mfma_f32_16x16x32_bf16(
                    a[fi], bb[fj], acc[fi][fj], 0, 0, 0);
    }

    const int col = lane & 15, r0q = (lane >> 4) * 4;
#pragma unroll
    for (int fi = 0; fi < 4; ++fi)
#pragma unroll
        for (int r = 0; r < 4; ++r) {
            const int o = m0 + wr * 64 + fi * 16 + r0q + r;
            const float bias = b_out[o];
#pragma unroll
            for (int fj = 0; fj < 4; ++fj)
                out[((size_t)b * CIN + o) * NPIX + n0 + wc * 64 + fj * 16 + col] =
                    acc[fi][fj][r] + bias;
        }
}

// ---------------------------------------------------------------------------
extern "C" void kernel_launch(void* const* d_in, const int* in_sizes, int n_in,
                              void* d_out, int out_size, void* d_ws, size_t ws_size,
                              hipStream_t stream)
{
    const float* x     = (const float*)d_in[0];
    const float* w_qkv = (const float*)d_in[1];
    const float* w_out = (const float*)d_in[2];
    const float* b_out = (const float*)d_in[3];
    float* out = (float*)d_out;

    char* ws = (char*)d_ws;
    unsigned short* xt2   = (unsigned short*)ws;                           // 32 MB
    unsigned short* xbf2  = (unsigned short*)(ws + (32ull << 20));         // 32 MB
    unsigned short* WkF   = (unsigned short*)(ws + (64ull << 20));         // 256 KB
    unsigned short* WvF   = (unsigned short*)(ws + (64ull << 20) + (256u << 10));
    unsigned short* WqTF  = (unsigned short*)(ws + (64ull << 20) + (512u << 10));
    unsigned short* WoF   = (unsigned short*)(ws + (64ull << 20) + (768u << 10));
    float*          S     = (float*)(ws + (65ull << 20));                  // 8 KB
    float*          G     = (float*)(ws + (66ull << 20));                  // 2 MB
    unsigned short* AbarF = (unsigned short*)(ws + (68ull << 20));         // 256 KB
    unsigned short* F2    = (unsigned short*)(ws + (69ull << 20));         // 512 KB

    hipMemsetAsync(S, 0, 2048 * sizeof(float), stream);
    hipMemsetAsync(G, 0, (size_t)16 * 32768 * sizeof(float), stream);
    xt_convert2<<<dim3(NPIX / 64, CIN / 64, NB), 256, 0, stream>>>(x, xt2, xbf2);
    wconv3<<<256, 256, 0, stream>>>(w_qkv, w_out, WkF, WvF, WqTF, WoF);
    kg_fused5<<<dim3(32, HEADS, NB), 512, 0, stream>>>(xt2, xbf2, WkF, G, S);
    c1_kernel<<<16, 256, 0, stream>>>(G, S, WvF, WqTF, AbarF);
    c2_kernel<<<dim3(4, NB), 256, 0, stream>>>(WoF, AbarF, F2);
    out_gemm3<<<dim3(NPIX / 128, CIN / 128, NB), 256, 0, stream>>>(xt2, F2, b_out, out);
}

// Round 9
// 149.745 us; speedup vs baseline: 1.1478x; 1.1478x over previous
//
#include <hip/hip_runtime.h>
#include <hip/hip_bf16.h>

#define HEADS 4
#define DH    128
#define CIN   256
#define NPIX  16384
#define NB    4
#define HID   512

typedef __attribute__((ext_vector_type(8))) short bf16x8;
typedef __attribute__((ext_vector_type(4))) float f32x4;

__device__ __forceinline__ unsigned short f2bfu(float f) {
    union { __hip_bfloat16 h; unsigned short u; } cv;
    cv.h = __float2bfloat16(f);
    return cv.u;
}

// ---- async global->LDS, 16B per lane --------------------------------------
typedef const __attribute__((address_space(1))) unsigned char* gas_t;
typedef __attribute__((address_space(3))) unsigned char* las_t;
__device__ __forceinline__ void glds16(const void* g, void* s) {
    __builtin_amdgcn_global_load_lds((gas_t)g, (las_t)s, 16, 0, 0);
}

// Fragment-tile: 16(row) x 32(k) bf16 = 512 ushorts, lane-major:
// element (row r, k) at us = (r + 16*(k>>3))*8 + (k&7); lane l owns us l*8..l*8+7.

// ---------------------------------------------------------------------------
// K0a: x[b][c][n] fp32 -> xt2 (frag tiles rows=n,k=c), xbf2 (frag tiles rows=c,k=n)
// grid (256, 4, 4), block 256
// ---------------------------------------------------------------------------
__global__ __launch_bounds__(256) void xt_convert2(const float* __restrict__ x,
                                                   unsigned short* __restrict__ xt2,
                                                   unsigned short* __restrict__ xbf2)
{
    __shared__ float tile[64][66];
    const int b = blockIdx.z, c0 = blockIdx.y * 64, n0 = blockIdx.x * 64;
    const int t = threadIdx.x, lane = t & 63, wid = t >> 6;
    const float* xb = x + ((size_t)b * CIN + c0) * NPIX + n0;
#pragma unroll
    for (int p = 0; p < 4; ++p) {
        const int c = p * 16 + (t >> 4);
        const int n = (t & 15) * 4;
        float4 v = *reinterpret_cast<const float4*>(xb + (size_t)c * NPIX + n);
        tile[c][n + 0] = v.x; tile[c][n + 1] = v.y;
        tile[c][n + 2] = v.z; tile[c][n + 3] = v.w;
    }
    __syncthreads();
    // xt2: tiles (n16, c32): idx = ((b*1024 + n/16)*8 + c/32)
#pragma unroll
    for (int rr = 0; rr < 2; ++rr) {
        const int tid  = wid * 2 + rr;
        const int n16l = tid >> 1, c32l = tid & 1;
        const int nl   = n16l * 16 + (lane & 15);
        const int cb   = c32l * 32 + (lane >> 4) * 8;
        unsigned short u8[8];
#pragma unroll
        for (int j = 0; j < 8; ++j) u8[j] = f2bfu(tile[cb + j][nl]);
        *reinterpret_cast<uint4*>(
            xt2 + (((size_t)b * 1024 + (n0 >> 4) + n16l) * 8 + (c0 >> 5) + c32l) * 512 + lane * 8)
            = *reinterpret_cast<const uint4*>(u8);
    }
    // xbf2: tiles (c16, n32): idx = ((b*16 + c/16)*512 + n/32)
#pragma unroll
    for (int rr = 0; rr < 2; ++rr) {
        const int tid  = wid * 2 + rr;
        const int c16l = tid >> 1, n32l = tid & 1;
        const int cr   = c16l * 16 + (lane & 15);
        const int nb   = n32l * 32 + (lane >> 4) * 8;
        unsigned short u8[8];
#pragma unroll
        for (int j = 0; j < 8; ++j) u8[j] = f2bfu(tile[cr][nb + j]);
        *reinterpret_cast<uint4*>(
            xbf2 + (((size_t)b * 16 + (c0 >> 4) + c16l) * 512 + (n0 >> 5) + n32l) * 512 + lane * 8)
            = *reinterpret_cast<const uint4*>(u8);
    }
}

// ---------------------------------------------------------------------------
// K0b: all weight frag tiles.
// ---------------------------------------------------------------------------
__global__ __launch_bounds__(256) void wconv3(const float* __restrict__ w_qkv,
                                              const float* __restrict__ w_out,
                                              unsigned short* __restrict__ WkF,
                                              unsigned short* __restrict__ WvF,
                                              unsigned short* __restrict__ WqTF,
                                              unsigned short* __restrict__ WoF)
{
    const int t = threadIdx.x, lane = t & 63, wid = t >> 6;
    const int tile = blockIdx.x * 4 + wid;
    unsigned short u8[8];
    unsigned short* dst;
    if (tile < 256) {                       // WkF [h][d16 8][c32 8]
        const int h = tile >> 6, d16 = (tile >> 3) & 7, c32 = tile & 7;
        const float* src = w_qkv + (size_t)(512 + h * 128 + d16 * 16 + (lane & 15)) * CIN
                         + c32 * 32 + (lane >> 4) * 8;
#pragma unroll
        for (int j = 0; j < 8; ++j) u8[j] = f2bfu(src[j]);
        dst = WkF + (size_t)tile * 512 + lane * 8;
    } else if (tile < 512) {                // WvF [h][e16 8][c32 8]
        const int t2 = tile - 256;
        const int h = t2 >> 6, e16 = (t2 >> 3) & 7, c32 = t2 & 7;
        const float* src = w_qkv + (size_t)(1024 + h * 128 + e16 * 16 + (lane & 15)) * CIN
                         + c32 * 32 + (lane >> 4) * 8;
#pragma unroll
        for (int j = 0; j < 8; ++j) u8[j] = f2bfu(src[j]);
        dst = WvF + (size_t)t2 * 512 + lane * 8;
    } else if (tile < 768) {                // WqTF [h][c16 16][d32 4]
        const int t2 = tile - 512;
        const int h = t2 >> 6, c16 = (t2 >> 2) & 15, d32 = t2 & 3;
#pragma unroll
        for (int j = 0; j < 8; ++j)
            u8[j] = f2bfu(w_qkv[(size_t)(h * 128 + d32 * 32 + (lane >> 4) * 8 + j) * CIN
                                + c16 * 16 + (lane & 15)]);
        dst = WqTF + (size_t)t2 * 512 + lane * 8;
    } else {                                // WoF [o16 16][m32 16]
        const int t2 = tile - 768;
        const int o16 = t2 >> 4, m32 = t2 & 15;
        const float* src = w_out + (size_t)(o16 * 16 + (lane & 15)) * HID
                         + m32 * 32 + (lane >> 4) * 8;
#pragma unroll
        for (int j = 0; j < 8; ++j) u8[j] = f2bfu(src[j]);
        dst = WoF + (size_t)t2 * 512 + lane * 8;
    }
    *reinterpret_cast<uint4*>(dst) = *reinterpret_cast<const uint4*>(u8);
}

// ---------------------------------------------------------------------------
// K1: fused kg — R6 structure (64n phases, 2 barriers, 8 waves, 144 KB LDS)
// + XCD co-location remap (the 4 h-blocks of one (ns,b) share all staged data
//   -> same XCD L2) + direct fp32 atomicAdd into G (g_reduce deleted).
// launch: 256 blocks x 512 threads.
// ---------------------------------------------------------------------------
__global__ __launch_bounds__(512, 2) void kg_fused6(const unsigned short* __restrict__ xt2,
                                                    const unsigned short* __restrict__ xbf2,
                                                    const unsigned short* __restrict__ WkF,
                                                    float* __restrict__ G,
                                                    float* __restrict__ S)
{
    __shared__ unsigned short sXT[2][32 * 512];   // 2 x 32 KB: 4 n16 x 8 c32 tiles
    __shared__ unsigned short sXB[2][32 * 512];   // 2 x 32 KB: 16 c16 x 2 n32 tiles
    __shared__ unsigned short sP[16 * 512];       // 16 KB: 8 d16 x 2 n32 tiles

    // ---- XCD co-location remap: wgid%8 ~ XCD; group (ns,b) -> one XCD ----
    const int wgid = blockIdx.x;
    const int xcd  = wgid & 7;
    const int k_   = wgid >> 3;         // 0..31
    const int h    = k_ & 3;
    const int g_   = xcd + 8 * (k_ >> 2);   // 0..63
    const int ns   = g_ & 15;
    const int b    = g_ >> 4;
    const int bh   = b * 4 + h;

    const int t = threadIdx.x, lane = t & 63, wid = t >> 6;
    const int wm = wid >> 1, wn = wid & 1;    // GEMM1: 4x2 waves -> 32d x 32n each
    const int wd = wid >> 2, wcq = wid & 3;   // GEMM2: 2x4 waves -> 64d x 64c each
    const int cl = lane & 15, r0q = (lane >> 4) * 4;

    // persistent Wk fragments (d16 = wm*2+fi, c32 = ks): 64 VGPR
    bf16x8 aW[2][8];
#pragma unroll
    for (int fi = 0; fi < 2; ++fi)
#pragma unroll
        for (int ks = 0; ks < 8; ++ks)
            aW[fi][ks] = *reinterpret_cast<const bf16x8*>(
                WkF + ((size_t)(h * 64 + (wm * 2 + fi) * 8 + ks)) * 512 + lane * 8);

    f32x4 accG[4][4] = {};
    float Sacc[8] = {};

    const unsigned short* xtb = xt2 + ((size_t)(b * 1024 + ns * 64) * 8) * 512;

#define STAGE_XT(nt_, buf_)                                                     \
    {                                                                           \
        const unsigned short* src_ = xtb + (size_t)(nt_) * 4 * 8 * 512;         \
        _Pragma("unroll")                                                       \
        for (int p = 0; p < 4; ++p) {                                           \
            const int tl = p * 8 + wid;                                         \
            glds16(src_ + (size_t)tl * 512 + lane * 8, sXT[buf_] + (size_t)tl * 512); \
        }                                                                       \
    }
#define STAGE_XB(nt_, buf_)                                                     \
    {                                                                           \
        const size_t nb32_ = (size_t)ns * 32 + (nt_) * 2;                       \
        _Pragma("unroll")                                                       \
        for (int p = 0; p < 4; ++p) {                                           \
            const int tl = p * 8 + wid;                                         \
            const int c16_ = tl >> 1, n32l_ = tl & 1;                           \
            glds16(xbf2 + (((size_t)(b * 16 + c16_)) * 512 + nb32_ + n32l_) * 512 + lane * 8, \
                   sXB[buf_] + (size_t)tl * 512);                               \
        }                                                                       \
    }

    STAGE_XT(0, 0);
    STAGE_XB(0, 0);
    __syncthreads();

    int cur = 0;
    for (int nt = 0; nt < 16; ++nt) {
        if (nt < 15) {               // issue next-tile stages BEFORE compute
            STAGE_XT(nt + 1, cur ^ 1);
            STAGE_XB(nt + 1, cur ^ 1);
        }

        // ---- GEMM1: logits 32d x 32n per wave, K=256 ----
        f32x4 acc1[2][2] = {};
#pragma unroll
        for (int ks = 0; ks < 8; ++ks) {
            bf16x8 bb[2];
#pragma unroll
            for (int fj = 0; fj < 2; ++fj)
                bb[fj] = *reinterpret_cast<const bf16x8*>(
                    &sXT[cur][((wn * 2 + fj) * 8 + ks) * 512 + lane * 8]);
#pragma unroll
            for (int fi = 0; fi < 2; ++fi)
#pragma unroll
                for (int fj = 0; fj < 2; ++fj)
                    acc1[fi][fj] = __builtin_amdgcn_mfma_f32_16x16x32_bf16(
                        aW[fi][ks], bb[fj], acc1[fi][fj], 0, 0, 0);
        }

        // ---- exp -> sP (frag-tiled) + rowsum ----
#pragma unroll
        for (int fi = 0; fi < 2; ++fi)
#pragma unroll
            for (int r = 0; r < 4; ++r) {
                float rs = 0.f;
#pragma unroll
                for (int fj = 0; fj < 2; ++fj) {
                    const float v = __expf(acc1[fi][fj][r]);
                    rs += v;
                    // element (row=r0q+r, k=fj*16+cl) of tile (d16=wm*2+fi, n32=wn)
                    const int us = ((r0q + r) + 16 * (fj * 2 + (cl >> 3))) * 8 + (cl & 7);
                    sP[((wm * 2 + fi) * 2 + wn) * 512 + us] = f2bfu(v);
                }
                Sacc[fi * 4 + r] += rs;
            }
        __syncthreads();   // sP ready; nt+1 stages still in flight

        // ---- GEMM2: G[64d x 64c] per wave += P * xbf (contract 64 n) ----
#pragma unroll
        for (int kn = 0; kn < 2; ++kn) {
            bf16x8 pa[4], bb[4];
#pragma unroll
            for (int fi = 0; fi < 4; ++fi)
                pa[fi] = *reinterpret_cast<const bf16x8*>(
                    &sP[((wd * 4 + fi) * 2 + kn) * 512 + lane * 8]);
#pragma unroll
            for (int fj = 0; fj < 4; ++fj)
                bb[fj] = *reinterpret_cast<const bf16x8*>(
                    &sXB[cur][((wcq * 4 + fj) * 2 + kn) * 512 + lane * 8]);
#pragma unroll
            for (int fi = 0; fi < 4; ++fi)
#pragma unroll
                for (int fj = 0; fj < 4; ++fj)
                    accG[fi][fj] = __builtin_amdgcn_mfma_f32_16x16x32_bf16(
                        pa[fi], bb[fj], accG[fi][fj], 0, 0, 0);
        }
        __syncthreads();   // drains nt+1 stages + WAR on bufs
        cur ^= 1;
    }
#undef STAGE_XT
#undef STAGE_XB

    // ---- S rowsums ----
#pragma unroll
    for (int i = 0; i < 8; ++i) {
        float v = Sacc[i];
        v += __shfl_xor(v, 1); v += __shfl_xor(v, 2);
        v += __shfl_xor(v, 4); v += __shfl_xor(v, 8);
        if (cl == 0) {
            const int d = wm * 32 + (i >> 2) * 16 + r0q + (i & 3);
            atomicAdd(&S[bh * 128 + d], v);
        }
    }

    // ---- G accumulate (direct, replaces Gp + g_reduce) ----
#pragma unroll
    for (int fi = 0; fi < 4; ++fi)
#pragma unroll
        for (int fj = 0; fj < 4; ++fj)
#pragma unroll
            for (int r = 0; r < 4; ++r) {
                const int d = wd * 64 + fi * 16 + r0q + r;
                const int c = wcq * 64 + fj * 16 + cl;
                atomicAdd(&G[(size_t)bh * 32768 + d * 256 + c], accG[fi][fj][r]);
            }
}

// ---------------------------------------------------------------------------
// C1: per bh: ctx = (G/S) x Wv^T, then Abar = ctx^T x Wq -> AbarF frag tiles.
// grid 16, block 256
// ---------------------------------------------------------------------------
__global__ __launch_bounds__(256) void c1_kernel(const float* __restrict__ G,
                                                 const float* __restrict__ S,
                                                 const unsigned short* __restrict__ WvF,
                                                 const unsigned short* __restrict__ WqTF,
                                                 unsigned short* __restrict__ AbarF)
{
    __shared__ unsigned short sCtx[32 * 512];
    const int t = threadIdx.x, lane = t & 63, wid = t >> 6;
    const int bh = blockIdx.x, b = bh >> 2, h = bh & 3;
    const int cl = lane & 15, r0q = (lane >> 4) * 4;
    const int wr = wid >> 1, wc = wid & 1;
    const float* Gb = G + (size_t)bh * 32768;

    float invs[4];
#pragma unroll
    for (int fi = 0; fi < 4; ++fi)
        invs[fi] = 1.0f / S[bh * 128 + wr * 64 + fi * 16 + cl];

    f32x4 acc[4][4] = {};
#pragma unroll
    for (int ks = 0; ks < 8; ++ks) {
        bf16x8 a[4], bb[4];
#pragma unroll
        for (int fi = 0; fi < 4; ++fi) {
            const float* gp = Gb + (size_t)(wr * 64 + fi * 16 + cl) * 256
                            + ks * 32 + (lane >> 4) * 8;
            const float4 v0 = *reinterpret_cast<const float4*>(gp);
            const float4 v1 = *reinterpret_cast<const float4*>(gp + 4);
            unsigned short u8[8] = {
                f2bfu(v0.x * invs[fi]), f2bfu(v0.y * invs[fi]),
                f2bfu(v0.z * invs[fi]), f2bfu(v0.w * invs[fi]),
                f2bfu(v1.x * invs[fi]), f2bfu(v1.y * invs[fi]),
                f2bfu(v1.z * invs[fi]), f2bfu(v1.w * invs[fi]) };
            a[fi] = *reinterpret_cast<const bf16x8*>(u8);
        }
#pragma unroll
        for (int fj = 0; fj < 4; ++fj)
            bb[fj] = *reinterpret_cast<const bf16x8*>(
                WvF + ((size_t)(h * 8 + wc * 4 + fj) * 8 + ks) * 512 + lane * 8);
#pragma unroll
        for (int fi = 0; fi < 4; ++fi)
#pragma unroll
            for (int fj = 0; fj < 4; ++fj)
                acc[fi][fj] = __builtin_amdgcn_mfma_f32_16x16x32_bf16(
                    a[fi], bb[fj], acc[fi][fj], 0, 0, 0);
    }

#pragma unroll
    for (int fi = 0; fi < 4; ++fi)
#pragma unroll
        for (int fj = 0; fj < 4; ++fj)
#pragma unroll
            for (int r = 0; r < 4; ++r) {
                const int us = (cl + 16 * ((fi & 1) * 2 + ((r0q + r) >> 3))) * 8 + ((r0q + r) & 7);
                sCtx[((wc * 4 + fj) * 4 + wr * 2 + (fi >> 1)) * 512 + us] = f2bfu(acc[fi][fj][r]);
            }
    __syncthreads();

    const int we = wid >> 1, wcq = wid & 1;
    f32x4 acc2[4][8] = {};
#pragma unroll
    for (int ks = 0; ks < 4; ++ks) {
        bf16x8 a2[4], b2[8];
#pragma unroll
        for (int fi = 0; fi < 4; ++fi)
            a2[fi] = *reinterpret_cast<const bf16x8*>(
                &sCtx[((we * 4 + fi) * 4 + ks) * 512 + lane * 8]);
#pragma unroll
        for (int fj = 0; fj < 8; ++fj)
            b2[fj] = *reinterpret_cast<const bf16x8*>(
                WqTF + ((size_t)(h * 16 + wcq * 8 + fj) * 4 + ks) * 512 + lane * 8);
#pragma unroll
        for (int fi = 0; fi < 4; ++fi)
#pragma unroll
            for (int fj = 0; fj < 8; ++fj)
                acc2[fi][fj] = __builtin_amdgcn_mfma_f32_16x16x32_bf16(
                    a2[fi], b2[fj], acc2[fi][fj], 0, 0, 0);
    }

#pragma unroll
    for (int fi = 0; fi < 4; ++fi)
#pragma unroll
        for (int fj = 0; fj < 8; ++fj)
#pragma unroll
            for (int r = 0; r < 4; ++r) {
                const int c16 = wcq * 8 + fj;
                const int m32 = h * 4 + we * 2 + (fi >> 1);
                const int us  = (cl + 16 * ((fi & 1) * 2 + ((r0q + r) >> 3))) * 8 + ((r0q + r) & 7);
                AbarF[((size_t)(b * 16 + c16) * 16 + m32) * 512 + us] = f2bfu(acc2[fi][fj][r]);
            }
}

// ---------------------------------------------------------------------------
// C2: F[b][256o x 64c] = Wo x Abar (K=512), no LDS.
// ---------------------------------------------------------------------------
__global__ __launch_bounds__(256) void c2_kernel(const unsigned short* __restrict__ WoF,
                                                 const unsigned short* __restrict__ AbarF,
                                                 unsigned short* __restrict__ F2)
{
    const int t = threadIdx.x, lane = t & 63, wid = t >> 6;
    const int csp = blockIdx.x, b = blockIdx.y;
    const int cl = lane & 15, r0q = (lane >> 4) * 4;

    f32x4 acc[4][4] = {};
#pragma unroll
    for (int ks = 0; ks < 16; ++ks) {
        bf16x8 a[4], bb[4];
#pragma unroll
        for (int fi = 0; fi < 4; ++fi)
            a[fi] = *reinterpret_cast<const bf16x8*>(
                WoF + ((size_t)(wid * 4 + fi) * 16 + ks) * 512 + lane * 8);
#pragma unroll
        for (int fj = 0; fj < 4; ++fj)
            bb[fj] = *reinterpret_cast<const bf16x8*>(
                AbarF + ((size_t)(b * 16 + csp * 4 + fj) * 16 + ks) * 512 + lane * 8);
#pragma unroll
        for (int fi = 0; fi < 4; ++fi)
#pragma unroll
            for (int fj = 0; fj < 4; ++fj)
                acc[fi][fj] = __builtin_amdgcn_mfma_f32_16x16x32_bf16(
                    a[fi], bb[fj], acc[fi][fj], 0, 0, 0);
    }

#pragma unroll
    for (int fi = 0; fi < 4; ++fi)
#pragma unroll
        for (int fj = 0; fj < 4; ++fj)
#pragma unroll
            for (int r = 0; r < 4; ++r) {
                const int o16 = wid * 4 + fi;
                const int c32 = csp * 2 + (fj >> 1);
                const int us  = ((r0q + r) + 16 * ((fj & 1) * 2 + (cl >> 3))) * 8 + (cl & 7);
                F2[((size_t)(b * 16 + o16) * 8 + c32) * 512 + us] = f2bfu(acc[fi][fj][r]);
            }
}

// ---------------------------------------------------------------------------
// K6: out GEMM.  Stage whole xt n-panel (64 KB) once; F2 direct from L2.
// grid (128, 2, 4), block 256 (2x2 waves of 64o x 64n)
// ---------------------------------------------------------------------------
__global__ __launch_bounds__(256, 2) void out_gemm3(const unsigned short* __restrict__ xt2,
                                                    const unsigned short* __restrict__ F2,
                                                    const float* __restrict__ b_out,
                                                    float* __restrict__ out)
{
    __shared__ unsigned short sXT[64 * 512];
    const int t = threadIdx.x, lane = t & 63, wid = t >> 6;
    const int n0 = blockIdx.x * 128, m0 = blockIdx.y * 128, b = blockIdx.z;
    const int wr = wid >> 1, wc = wid & 1;

    const unsigned short* src = xt2 + ((size_t)(b * 1024 + (n0 >> 4)) * 8) * 512;
#pragma unroll
    for (int p = 0; p < 16; ++p) {
        const int tl = p * 4 + wid;
        glds16(src + (size_t)tl * 512 + lane * 8, sXT + (size_t)tl * 512);
    }
    __syncthreads();

    f32x4 acc[4][4] = {};
#pragma unroll
    for (int ks = 0; ks < 8; ++ks) {
        bf16x8 a[4], bb[4];
#pragma unroll
        for (int fi = 0; fi < 4; ++fi)
            a[fi] = *reinterpret_cast<const bf16x8*>(
                F2 + (((size_t)b * 16 + (m0 >> 4) + wr * 4 + fi) * 8 + ks) * 512 + lane * 8);
#pragma unroll
        for (int fj = 0; fj < 4; ++fj)
            bb[fj] = *reinterpret_cast<const bf16x8*>(
                &sXT[((wc * 4 + fj) * 8 + ks) * 512 + lane * 8]);
#pragma unroll
        for (int fi = 0; fi < 4; ++fi)
#pragma unroll
            for (int fj = 0; fj < 4; ++fj)
                acc[fi][fj] = __builtin_amdgcn_mfma_f32_16x16x32_bf16(
                    a[fi], bb[fj], acc[fi][fj], 0, 0, 0);
    }

    const int col = lane & 15, r0q = (lane >> 4) * 4;
#pragma unroll
    for (int fi = 0; fi < 4; ++fi)
#pragma unroll
        for (int r = 0; r < 4; ++r) {
            const int o = m0 + wr * 64 + fi * 16 + r0q + r;
            const float bias = b_out[o];
#pragma unroll
            for (int fj = 0; fj < 4; ++fj)
                out[((size_t)b * CIN + o) * NPIX + n0 + wc * 64 + fj * 16 + col] =
                    acc[fi][fj][r] + bias;
        }
}

// ---------------------------------------------------------------------------
extern "C" void kernel_launch(void* const* d_in, const int* in_sizes, int n_in,
                              void* d_out, int out_size, void* d_ws, size_t ws_size,
                              hipStream_t stream)
{
    const float* x     = (const float*)d_in[0];
    const float* w_qkv = (const float*)d_in[1];
    const float* w_out = (const float*)d_in[2];
    const float* b_out = (const float*)d_in[3];
    float* out = (float*)d_out;

    char* ws = (char*)d_ws;
    unsigned short* xt2   = (unsigned short*)ws;                           // 32 MB
    unsigned short* xbf2  = (unsigned short*)(ws + (32ull << 20));         // 32 MB
    unsigned short* WkF   = (unsigned short*)(ws + (64ull << 20));         // 256 KB
    unsigned short* WvF   = (unsigned short*)(ws + (64ull << 20) + (256u << 10));
    unsigned short* WqTF  = (unsigned short*)(ws + (64ull << 20) + (512u << 10));
    unsigned short* WoF   = (unsigned short*)(ws + (64ull << 20) + (768u << 10));
    float*          S     = (float*)(ws + (65ull << 20));                  // 8 KB
    float*          G     = (float*)(ws + (66ull << 20));                  // 2 MB
    unsigned short* AbarF = (unsigned short*)(ws + (68ull << 20));         // 256 KB
    unsigned short* F2    = (unsigned short*)(ws + (69ull << 20));         // 512 KB

    hipMemsetAsync(S, 0, 2048 * sizeof(float), stream);
    hipMemsetAsync(G, 0, (size_t)16 * 32768 * sizeof(float), stream);
    xt_convert2<<<dim3(NPIX / 64, CIN / 64, NB), 256, 0, stream>>>(x, xt2, xbf2);
    wconv3<<<256, 256, 0, stream>>>(w_qkv, w_out, WkF, WvF, WqTF, WoF);
    kg_fused6<<<256, 512, 0, stream>>>(xt2, xbf2, WkF, G, S);
    c1_kernel<<<16, 256, 0, stream>>>(G, S, WvF, WqTF, AbarF);
    c2_kernel<<<dim3(4, NB), 256, 0, stream>>>(WoF, AbarF, F2);
    out_gemm3<<<dim3(NPIX / 128, CIN / 128, NB), 256, 0, stream>>>(xt2, F2, b_out, out);
}

// Round 10
// 136.042 us; speedup vs baseline: 1.2634x; 1.1007x over previous
//
#include <hip/hip_runtime.h>
#include <hip/hip_bf16.h>

#define HEADS 4
#define DH    128
#define CIN   256
#define NPIX  16384
#define NB    4
#define HID   512

typedef __attribute__((ext_vector_type(8))) short bf16x8;
typedef __attribute__((ext_vector_type(4))) float f32x4;

__device__ __forceinline__ unsigned short f2bfu(float f) {
    union { __hip_bfloat16 h; unsigned short u; } cv;
    cv.h = __float2bfloat16(f);
    return cv.u;
}

// ---- async global->LDS, 16B per lane --------------------------------------
typedef const __attribute__((address_space(1))) unsigned char* gas_t;
typedef __attribute__((address_space(3))) unsigned char* las_t;
__device__ __forceinline__ void glds16(const void* g, void* s) {
    __builtin_amdgcn_global_load_lds((gas_t)g, (las_t)s, 16, 0, 0);
}

// Fragment-tile: 16(row) x 32(k) bf16 = 512 ushorts, lane-major:
// element (row r, k) at us = (r + 16*(k>>3))*8 + (k&7); lane l owns us l*8..l*8+7.

// ---------------------------------------------------------------------------
// K0a: x[b][c][n] fp32 -> xt2 (frag tiles rows=n,k=c), xbf2 (frag tiles rows=c,k=n)
// grid (256, 4, 4), block 256
// ---------------------------------------------------------------------------
__global__ __launch_bounds__(256) void xt_convert2(const float* __restrict__ x,
                                                   unsigned short* __restrict__ xt2,
                                                   unsigned short* __restrict__ xbf2)
{
    __shared__ float tile[64][66];
    const int b = blockIdx.z, c0 = blockIdx.y * 64, n0 = blockIdx.x * 64;
    const int t = threadIdx.x, lane = t & 63, wid = t >> 6;
    const float* xb = x + ((size_t)b * CIN + c0) * NPIX + n0;
#pragma unroll
    for (int p = 0; p < 4; ++p) {
        const int c = p * 16 + (t >> 4);
        const int n = (t & 15) * 4;
        float4 v = *reinterpret_cast<const float4*>(xb + (size_t)c * NPIX + n);
        tile[c][n + 0] = v.x; tile[c][n + 1] = v.y;
        tile[c][n + 2] = v.z; tile[c][n + 3] = v.w;
    }
    __syncthreads();
    // xt2: tiles (n16, c32): idx = ((b*1024 + n/16)*8 + c/32)
#pragma unroll
    for (int rr = 0; rr < 2; ++rr) {
        const int tid  = wid * 2 + rr;
        const int n16l = tid >> 1, c32l = tid & 1;
        const int nl   = n16l * 16 + (lane & 15);
        const int cb   = c32l * 32 + (lane >> 4) * 8;
        unsigned short u8[8];
#pragma unroll
        for (int j = 0; j < 8; ++j) u8[j] = f2bfu(tile[cb + j][nl]);
        *reinterpret_cast<uint4*>(
            xt2 + (((size_t)b * 1024 + (n0 >> 4) + n16l) * 8 + (c0 >> 5) + c32l) * 512 + lane * 8)
            = *reinterpret_cast<const uint4*>(u8);
    }
    // xbf2: tiles (c16, n32): idx = ((b*16 + c/16)*512 + n/32)
#pragma unroll
    for (int rr = 0; rr < 2; ++rr) {
        const int tid  = wid * 2 + rr;
        const int c16l = tid >> 1, n32l = tid & 1;
        const int cr   = c16l * 16 + (lane & 15);
        const int nb   = n32l * 32 + (lane >> 4) * 8;
        unsigned short u8[8];
#pragma unroll
        for (int j = 0; j < 8; ++j) u8[j] = f2bfu(tile[cr][nb + j]);
        *reinterpret_cast<uint4*>(
            xbf2 + (((size_t)b * 16 + (c0 >> 4) + c16l) * 512 + (n0 >> 5) + n32l) * 512 + lane * 8)
            = *reinterpret_cast<const uint4*>(u8);
    }
}

// ---------------------------------------------------------------------------
// K0b: all weight frag tiles.
// ---------------------------------------------------------------------------
__global__ __launch_bounds__(256) void wconv3(const float* __restrict__ w_qkv,
                                              const float* __restrict__ w_out,
                                              unsigned short* __restrict__ WkF,
                                              unsigned short* __restrict__ WvF,
                                              unsigned short* __restrict__ WqTF,
                                              unsigned short* __restrict__ WoF)
{
    const int t = threadIdx.x, lane = t & 63, wid = t >> 6;
    const int tile = blockIdx.x * 4 + wid;
    unsigned short u8[8];
    unsigned short* dst;
    if (tile < 256) {                       // WkF [h][d16 8][c32 8]
        const int h = tile >> 6, d16 = (tile >> 3) & 7, c32 = tile & 7;
        const float* src = w_qkv + (size_t)(512 + h * 128 + d16 * 16 + (lane & 15)) * CIN
                         + c32 * 32 + (lane >> 4) * 8;
#pragma unroll
        for (int j = 0; j < 8; ++j) u8[j] = f2bfu(src[j]);
        dst = WkF + (size_t)tile * 512 + lane * 8;
    } else if (tile < 512) {                // WvF [h][e16 8][c32 8]
        const int t2 = tile - 256;
        const int h = t2 >> 6, e16 = (t2 >> 3) & 7, c32 = t2 & 7;
        const float* src = w_qkv + (size_t)(1024 + h * 128 + e16 * 16 + (lane & 15)) * CIN
                         + c32 * 32 + (lane >> 4) * 8;
#pragma unroll
        for (int j = 0; j < 8; ++j) u8[j] = f2bfu(src[j]);
        dst = WvF + (size_t)t2 * 512 + lane * 8;
    } else if (tile < 768) {                // WqTF [h][c16 16][d32 4]
        const int t2 = tile - 512;
        const int h = t2 >> 6, c16 = (t2 >> 2) & 15, d32 = t2 & 3;
#pragma unroll
        for (int j = 0; j < 8; ++j)
            u8[j] = f2bfu(w_qkv[(size_t)(h * 128 + d32 * 32 + (lane >> 4) * 8 + j) * CIN
                                + c16 * 16 + (lane & 15)]);
        dst = WqTF + (size_t)t2 * 512 + lane * 8;
    } else {                                // WoF [o16 16][m32 16]
        const int t2 = tile - 768;
        const int o16 = t2 >> 4, m32 = t2 & 15;
        const float* src = w_out + (size_t)(o16 * 16 + (lane & 15)) * HID
                         + m32 * 32 + (lane >> 4) * 8;
#pragma unroll
        for (int j = 0; j < 8; ++j) u8[j] = f2bfu(src[j]);
        dst = WoF + (size_t)t2 * 512 + lane * 8;
    }
    *reinterpret_cast<uint4*>(dst) = *reinterpret_cast<const uint4*>(u8);
}

// ---------------------------------------------------------------------------
// K1: fused kg — R6 structure (64n phases, 2 barriers, 8 waves, 144 KB LDS)
// + XCD co-location remap.  Epilogue: plain coalesced stores to Gp[ns]
// (NO atomics — R9 showed the atomic tail costs ~18 us).
// launch: 256 blocks x 512 threads.
// ---------------------------------------------------------------------------
__global__ __launch_bounds__(512, 2) void kg_fused6(const unsigned short* __restrict__ xt2,
                                                    const unsigned short* __restrict__ xbf2,
                                                    const unsigned short* __restrict__ WkF,
                                                    float* __restrict__ Gp,
                                                    float* __restrict__ S)
{
    __shared__ unsigned short sXT[2][32 * 512];   // 2 x 32 KB: 4 n16 x 8 c32 tiles
    __shared__ unsigned short sXB[2][32 * 512];   // 2 x 32 KB: 16 c16 x 2 n32 tiles
    __shared__ unsigned short sP[16 * 512];       // 16 KB: 8 d16 x 2 n32 tiles

    // ---- XCD co-location remap: wgid%8 ~ XCD; group (ns,b) -> one XCD ----
    const int wgid = blockIdx.x;
    const int xcd  = wgid & 7;
    const int k_   = wgid >> 3;         // 0..31
    const int h    = k_ & 3;
    const int g_   = xcd + 8 * (k_ >> 2);   // 0..63
    const int ns   = g_ & 15;
    const int b    = g_ >> 4;
    const int bh   = b * 4 + h;

    const int t = threadIdx.x, lane = t & 63, wid = t >> 6;
    const int wm = wid >> 1, wn = wid & 1;    // GEMM1: 4x2 waves -> 32d x 32n each
    const int wd = wid >> 2, wcq = wid & 3;   // GEMM2: 2x4 waves -> 64d x 64c each
    const int cl = lane & 15, r0q = (lane >> 4) * 4;

    // persistent Wk fragments (d16 = wm*2+fi, c32 = ks): 64 VGPR
    bf16x8 aW[2][8];
#pragma unroll
    for (int fi = 0; fi < 2; ++fi)
#pragma unroll
        for (int ks = 0; ks < 8; ++ks)
            aW[fi][ks] = *reinterpret_cast<const bf16x8*>(
                WkF + ((size_t)(h * 64 + (wm * 2 + fi) * 8 + ks)) * 512 + lane * 8);

    f32x4 accG[4][4] = {};
    float Sacc[8] = {};

    const unsigned short* xtb = xt2 + ((size_t)(b * 1024 + ns * 64) * 8) * 512;

#define STAGE_XT(nt_, buf_)                                                     \
    {                                                                           \
        const unsigned short* src_ = xtb + (size_t)(nt_) * 4 * 8 * 512;         \
        _Pragma("unroll")                                                       \
        for (int p = 0; p < 4; ++p) {                                           \
            const int tl = p * 8 + wid;                                         \
            glds16(src_ + (size_t)tl * 512 + lane * 8, sXT[buf_] + (size_t)tl * 512); \
        }                                                                       \
    }
#define STAGE_XB(nt_, buf_)                                                     \
    {                                                                           \
        const size_t nb32_ = (size_t)ns * 32 + (nt_) * 2;                       \
        _Pragma("unroll")                                                       \
        for (int p = 0; p < 4; ++p) {                                           \
            const int tl = p * 8 + wid;                                         \
            const int c16_ = tl >> 1, n32l_ = tl & 1;                           \
            glds16(xbf2 + (((size_t)(b * 16 + c16_)) * 512 + nb32_ + n32l_) * 512 + lane * 8, \
                   sXB[buf_] + (size_t)tl * 512);                               \
        }                                                                       \
    }

    STAGE_XT(0, 0);
    STAGE_XB(0, 0);
    __syncthreads();

    int cur = 0;
    for (int nt = 0; nt < 16; ++nt) {
        if (nt < 15) {               // issue next-tile stages BEFORE compute
            STAGE_XT(nt + 1, cur ^ 1);
            STAGE_XB(nt + 1, cur ^ 1);
        }

        // ---- GEMM1: logits 32d x 32n per wave, K=256 ----
        f32x4 acc1[2][2] = {};
#pragma unroll
        for (int ks = 0; ks < 8; ++ks) {
            bf16x8 bb[2];
#pragma unroll
            for (int fj = 0; fj < 2; ++fj)
                bb[fj] = *reinterpret_cast<const bf16x8*>(
                    &sXT[cur][((wn * 2 + fj) * 8 + ks) * 512 + lane * 8]);
#pragma unroll
            for (int fi = 0; fi < 2; ++fi)
#pragma unroll
                for (int fj = 0; fj < 2; ++fj)
                    acc1[fi][fj] = __builtin_amdgcn_mfma_f32_16x16x32_bf16(
                        aW[fi][ks], bb[fj], acc1[fi][fj], 0, 0, 0);
        }

        // ---- exp -> sP (frag-tiled) + rowsum ----
#pragma unroll
        for (int fi = 0; fi < 2; ++fi)
#pragma unroll
            for (int r = 0; r < 4; ++r) {
                float rs = 0.f;
#pragma unroll
                for (int fj = 0; fj < 2; ++fj) {
                    const float v = __expf(acc1[fi][fj][r]);
                    rs += v;
                    // element (row=r0q+r, k=fj*16+cl) of tile (d16=wm*2+fi, n32=wn)
                    const int us = ((r0q + r) + 16 * (fj * 2 + (cl >> 3))) * 8 + (cl & 7);
                    sP[((wm * 2 + fi) * 2 + wn) * 512 + us] = f2bfu(v);
                }
                Sacc[fi * 4 + r] += rs;
            }
        __syncthreads();   // sP ready; nt+1 stages still in flight

        // ---- GEMM2: G[64d x 64c] per wave += P * xbf (contract 64 n) ----
#pragma unroll
        for (int kn = 0; kn < 2; ++kn) {
            bf16x8 pa[4], bb[4];
#pragma unroll
            for (int fi = 0; fi < 4; ++fi)
                pa[fi] = *reinterpret_cast<const bf16x8*>(
                    &sP[((wd * 4 + fi) * 2 + kn) * 512 + lane * 8]);
#pragma unroll
            for (int fj = 0; fj < 4; ++fj)
                bb[fj] = *reinterpret_cast<const bf16x8*>(
                    &sXB[cur][((wcq * 4 + fj) * 2 + kn) * 512 + lane * 8]);
#pragma unroll
            for (int fi = 0; fi < 4; ++fi)
#pragma unroll
                for (int fj = 0; fj < 4; ++fj)
                    accG[fi][fj] = __builtin_amdgcn_mfma_f32_16x16x32_bf16(
                        pa[fi], bb[fj], accG[fi][fj], 0, 0, 0);
        }
        __syncthreads();   // drains nt+1 stages + WAR on bufs
        cur ^= 1;
    }
#undef STAGE_XT
#undef STAGE_XB

    // ---- S rowsums ----
#pragma unroll
    for (int i = 0; i < 8; ++i) {
        float v = Sacc[i];
        v += __shfl_xor(v, 1); v += __shfl_xor(v, 2);
        v += __shfl_xor(v, 4); v += __shfl_xor(v, 8);
        if (cl == 0) {
            const int d = wm * 32 + (i >> 2) * 16 + r0q + (i & 3);
            atomicAdd(&S[bh * 128 + d], v);
        }
    }

    // ---- G partial write (plain coalesced stores) ----
    float* gp = Gp + (size_t)(ns * 16 + bh) * (128 * 256);
#pragma unroll
    for (int fi = 0; fi < 4; ++fi)
#pragma unroll
        for (int fj = 0; fj < 4; ++fj)
#pragma unroll
            for (int r = 0; r < 4; ++r)
                gp[(size_t)(wd * 64 + fi * 16 + r0q + r) * 256 + wcq * 64 + fj * 16 + cl]
                    = accG[fi][fj][r];
}

// K2: G[bh][d][c] = sum over 16 splits (raw; c1 applies 1/S)
__global__ __launch_bounds__(256) void g_reduce2(const float* __restrict__ Gp,
                                                 float* __restrict__ G)
{
    const int idx = blockIdx.x * 256 + threadIdx.x;   // 16 * 32768
    const int bh = idx >> 15, dc = idx & 32767;
    float s = 0.f;
#pragma unroll
    for (int k = 0; k < 16; ++k)
        s += Gp[((size_t)k * 16 + bh) * 32768 + dc];
    G[idx] = s;
}

// ---------------------------------------------------------------------------
// C1: per bh: ctx = (G/S) x Wv^T, then Abar = ctx^T x Wq -> AbarF frag tiles.
// grid 16, block 256
// ---------------------------------------------------------------------------
__global__ __launch_bounds__(256) void c1_kernel(const float* __restrict__ G,
                                                 const float* __restrict__ S,
                                                 const unsigned short* __restrict__ WvF,
                                                 const unsigned short* __restrict__ WqTF,
                                                 unsigned short* __restrict__ AbarF)
{
    __shared__ unsigned short sCtx[32 * 512];
    const int t = threadIdx.x, lane = t & 63, wid = t >> 6;
    const int bh = blockIdx.x, b = bh >> 2, h = bh & 3;
    const int cl = lane & 15, r0q = (lane >> 4) * 4;
    const int wr = wid >> 1, wc = wid & 1;
    const float* Gb = G + (size_t)bh * 32768;

    float invs[4];
#pragma unroll
    for (int fi = 0; fi < 4; ++fi)
        invs[fi] = 1.0f / S[bh * 128 + wr * 64 + fi * 16 + cl];

    f32x4 acc[4][4] = {};
#pragma unroll
    for (int ks = 0; ks < 8; ++ks) {
        bf16x8 a[4], bb[4];
#pragma unroll
        for (int fi = 0; fi < 4; ++fi) {
            const float* gp = Gb + (size_t)(wr * 64 + fi * 16 + cl) * 256
                            + ks * 32 + (lane >> 4) * 8;
            const float4 v0 = *reinterpret_cast<const float4*>(gp);
            const float4 v1 = *reinterpret_cast<const float4*>(gp + 4);
            unsigned short u8[8] = {
                f2bfu(v0.x * invs[fi]), f2bfu(v0.y * invs[fi]),
                f2bfu(v0.z * invs[fi]), f2bfu(v0.w * invs[fi]),
                f2bfu(v1.x * invs[fi]), f2bfu(v1.y * invs[fi]),
                f2bfu(v1.z * invs[fi]), f2bfu(v1.w * invs[fi]) };
            a[fi] = *reinterpret_cast<const bf16x8*>(u8);
        }
#pragma unroll
        for (int fj = 0; fj < 4; ++fj)
            bb[fj] = *reinterpret_cast<const bf16x8*>(
                WvF + ((size_t)(h * 8 + wc * 4 + fj) * 8 + ks) * 512 + lane * 8);
#pragma unroll
        for (int fi = 0; fi < 4; ++fi)
#pragma unroll
            for (int fj = 0; fj < 4; ++fj)
                acc[fi][fj] = __builtin_amdgcn_mfma_f32_16x16x32_bf16(
                    a[fi], bb[fj], acc[fi][fj], 0, 0, 0);
    }

#pragma unroll
    for (int fi = 0; fi < 4; ++fi)
#pragma unroll
        for (int fj = 0; fj < 4; ++fj)
#pragma unroll
            for (int r = 0; r < 4; ++r) {
                const int us = (cl + 16 * ((fi & 1) * 2 + ((r0q + r) >> 3))) * 8 + ((r0q + r) & 7);
                sCtx[((wc * 4 + fj) * 4 + wr * 2 + (fi >> 1)) * 512 + us] = f2bfu(acc[fi][fj][r]);
            }
    __syncthreads();

    const int we = wid >> 1, wcq = wid & 1;
    f32x4 acc2[4][8] = {};
#pragma unroll
    for (int ks = 0; ks < 4; ++ks) {
        bf16x8 a2[4], b2[8];
#pragma unroll
        for (int fi = 0; fi < 4; ++fi)
            a2[fi] = *reinterpret_cast<const bf16x8*>(
                &sCtx[((we * 4 + fi) * 4 + ks) * 512 + lane * 8]);
#pragma unroll
        for (int fj = 0; fj < 8; ++fj)
            b2[fj] = *reinterpret_cast<const bf16x8*>(
                WqTF + ((size_t)(h * 16 + wcq * 8 + fj) * 4 + ks) * 512 + lane * 8);
#pragma unroll
        for (int fi = 0; fi < 4; ++fi)
#pragma unroll
            for (int fj = 0; fj < 8; ++fj)
                acc2[fi][fj] = __builtin_amdgcn_mfma_f32_16x16x32_bf16(
                    a2[fi], b2[fj], acc2[fi][fj], 0, 0, 0);
    }

#pragma unroll
    for (int fi = 0; fi < 4; ++fi)
#pragma unroll
        for (int fj = 0; fj < 8; ++fj)
#pragma unroll
            for (int r = 0; r < 4; ++r) {
                const int c16 = wcq * 8 + fj;
                const int m32 = h * 4 + we * 2 + (fi >> 1);
                const int us  = (cl + 16 * ((fi & 1) * 2 + ((r0q + r) >> 3))) * 8 + ((r0q + r) & 7);
                AbarF[((size_t)(b * 16 + c16) * 16 + m32) * 512 + us] = f2bfu(acc2[fi][fj][r]);
            }
}

// ---------------------------------------------------------------------------
// C2: F[b][256o x 64c] = Wo x Abar (K=512), no LDS.
// ---------------------------------------------------------------------------
__global__ __launch_bounds__(256) void c2_kernel(const unsigned short* __restrict__ WoF,
                                                 const unsigned short* __restrict__ AbarF,
                                                 unsigned short* __restrict__ F2)
{
    const int t = threadIdx.x, lane = t & 63, wid = t >> 6;
    const int csp = blockIdx.x, b = blockIdx.y;
    const int cl = lane & 15, r0q = (lane >> 4) * 4;

    f32x4 acc[4][4] = {};
#pragma unroll
    for (int ks = 0; ks < 16; ++ks) {
        bf16x8 a[4], bb[4];
#pragma unroll
        for (int fi = 0; fi < 4; ++fi)
            a[fi] = *reinterpret_cast<const bf16x8*>(
                WoF + ((size_t)(wid * 4 + fi) * 16 + ks) * 512 + lane * 8);
#pragma unroll
        for (int fj = 0; fj < 4; ++fj)
            bb[fj] = *reinterpret_cast<const bf16x8*>(
                AbarF + ((size_t)(b * 16 + csp * 4 + fj) * 16 + ks) * 512 + lane * 8);
#pragma unroll
        for (int fi = 0; fi < 4; ++fi)
#pragma unroll
            for (int fj = 0; fj < 4; ++fj)
                acc[fi][fj] = __builtin_amdgcn_mfma_f32_16x16x32_bf16(
                    a[fi], bb[fj], acc[fi][fj], 0, 0, 0);
    }

#pragma unroll
    for (int fi = 0; fi < 4; ++fi)
#pragma unroll
        for (int fj = 0; fj < 4; ++fj)
#pragma unroll
            for (int r = 0; r < 4; ++r) {
                const int o16 = wid * 4 + fi;
                const int c32 = csp * 2 + (fj >> 1);
                const int us  = ((r0q + r) + 16 * ((fj & 1) * 2 + (cl >> 3))) * 8 + (cl & 7);
                F2[((size_t)(b * 16 + o16) * 8 + c32) * 512 + us] = f2bfu(acc[fi][fj][r]);
            }
}

// ---------------------------------------------------------------------------
// K6: out GEMM.  Stage whole xt n-panel (64 KB) once; F2 direct from L2.
// grid (128, 2, 4), block 256 (2x2 waves of 64o x 64n)
// ---------------------------------------------------------------------------
__global__ __launch_bounds__(256, 2) void out_gemm3(const unsigned short* __restrict__ xt2,
                                                    const unsigned short* __restrict__ F2,
                                                    const float* __restrict__ b_out,
                                                    float* __restrict__ out)
{
    __shared__ unsigned short sXT[64 * 512];
    const int t = threadIdx.x, lane = t & 63, wid = t >> 6;
    const int n0 = blockIdx.x * 128, m0 = blockIdx.y * 128, b = blockIdx.z;
    const int wr = wid >> 1, wc = wid & 1;

    const unsigned short* src = xt2 + ((size_t)(b * 1024 + (n0 >> 4)) * 8) * 512;
#pragma unroll
    for (int p = 0; p < 16; ++p) {
        const int tl = p * 4 + wid;
        glds16(src + (size_t)tl * 512 + lane * 8, sXT + (size_t)tl * 512);
    }
    __syncthreads();

    f32x4 acc[4][4] = {};
#pragma unroll
    for (int ks = 0; ks < 8; ++ks) {
        bf16x8 a[4], bb[4];
#pragma unroll
        for (int fi = 0; fi < 4; ++fi)
            a[fi] = *reinterpret_cast<const bf16x8*>(
                F2 + (((size_t)b * 16 + (m0 >> 4) + wr * 4 + fi) * 8 + ks) * 512 + lane * 8);
#pragma unroll
        for (int fj = 0; fj < 4; ++fj)
            bb[fj] = *reinterpret_cast<const bf16x8*>(
                &sXT[((wc * 4 + fj) * 8 + ks) * 512 + lane * 8]);
#pragma unroll
        for (int fi = 0; fi < 4; ++fi)
#pragma unroll
            for (int fj = 0; fj < 4; ++fj)
                acc[fi][fj] = __builtin_amdgcn_mfma_f32_16x16x32_bf16(
                    a[fi], bb[fj], acc[fi][fj], 0, 0, 0);
    }

    const int col = lane & 15, r0q = (lane >> 4) * 4;
#pragma unroll
    for (int fi = 0; fi < 4; ++fi)
#pragma unroll
        for (int r = 0; r < 4; ++r) {
            const int o = m0 + wr * 64 + fi * 16 + r0q + r;
            const float bias = b_out[o];
#pragma unroll
            for (int fj = 0; fj < 4; ++fj)
                out[((size_t)b * CIN + o) * NPIX + n0 + wc * 64 + fj * 16 + col] =
                    acc[fi][fj][r] + bias;
        }
}

// ---------------------------------------------------------------------------
extern "C" void kernel_launch(void* const* d_in, const int* in_sizes, int n_in,
                              void* d_out, int out_size, void* d_ws, size_t ws_size,
                              hipStream_t stream)
{
    const float* x     = (const float*)d_in[0];
    const float* w_qkv = (const float*)d_in[1];
    const float* w_out = (const float*)d_in[2];
    const float* b_out = (const float*)d_in[3];
    float* out = (float*)d_out;

    char* ws = (char*)d_ws;
    unsigned short* xt2   = (unsigned short*)ws;                           // 32 MB
    unsigned short* xbf2  = (unsigned short*)(ws + (32ull << 20));         // 32 MB
    unsigned short* WkF   = (unsigned short*)(ws + (64ull << 20));         // 256 KB
    unsigned short* WvF   = (unsigned short*)(ws + (64ull << 20) + (256u << 10));
    unsigned short* WqTF  = (unsigned short*)(ws + (64ull << 20) + (512u << 10));
    unsigned short* WoF   = (unsigned short*)(ws + (64ull << 20) + (768u << 10));
    float*          S     = (float*)(ws + (65ull << 20));                  // 8 KB
    float*          G     = (float*)(ws + (66ull << 20));                  // 2 MB
    unsigned short* AbarF = (unsigned short*)(ws + (68ull << 20));         // 256 KB
    unsigned short* F2    = (unsigned short*)(ws + (69ull << 20));         // 512 KB
    float*          Gp    = (float*)(ws + (72ull << 20));                  // 33.5 MB

    hipMemsetAsync(S, 0, 2048 * sizeof(float), stream);
    xt_convert2<<<dim3(NPIX / 64, CIN / 64, NB), 256, 0, stream>>>(x, xt2, xbf2);
    wconv3<<<256, 256, 0, stream>>>(w_qkv, w_out, WkF, WvF, WqTF, WoF);
    kg_fused6<<<256, 512, 0, stream>>>(xt2, xbf2, WkF, Gp, S);
    g_reduce2<<<2048, 256, 0, stream>>>(Gp, G);
    c1_kernel<<<16, 256, 0, stream>>>(G, S, WvF, WqTF, AbarF);
    c2_kernel<<<dim3(4, NB), 256, 0, stream>>>(WoF, AbarF, F2);
    out_gemm3<<<dim3(NPIX / 128, CIN / 128, NB), 256, 0, stream>>>(xt2, F2, b_out, out);
}